// Round 17
// baseline (47.526 us; speedup 1.0000x reference)
//
#include <hip/hip_runtime.h>
#include <hip/hip_bf16.h>

#define B_    4
#define CIN_  64
#define H_    128
#define W_    128
#define COUT_ 64
#define KK_   9
#define OFFC_ 18
#define HW_   (H_*W_)
#define TILE_ 64
#define ZOFF  (B_ * HW_ * 64)   // zeroed pad row (64 halfs) appended to xt

typedef _Float16 hf8 __attribute__((ext_vector_type(8)));   // 8 fp16 (4 VGPRs)
typedef float f32x4  __attribute__((ext_vector_type(4)));

__device__ inline _Float16 f2h(float f) { return (_Float16)f; }

// ---------------------------------------------------------------------------
// Prep (single launch): blocks 0..1023 transpose x -> NHWC fp16;
// blocks 1024..1167 repack weights to fp16 MFMA layout; block 1024 also
// zeroes the xt pad row.
// ---------------------------------------------------------------------------
__global__ __launch_bounds__(256) void prep_all(
    const float* __restrict__ x,
    const float* __restrict__ ow, const float* __restrict__ dw,
    _Float16* __restrict__ xt, _Float16* __restrict__ dwh, _Float16* __restrict__ owh)
{
    const int tid = threadIdx.x;
    const int bid = blockIdx.x;
    if (bid < 1024) {
        const int b  = bid >> 8;
        const int pb = bid & 255;
        const int p  = tid & 63;
        const int g  = tid >> 6;             // channel group 0..3 (16 ch)
        const int pix = pb * 64 + p;
        const float* src = x + ((size_t)b * CIN_ + g * 16) * HW_ + pix;
        _Float16 vals[16];
        #pragma unroll
        for (int j = 0; j < 16; ++j) vals[j] = f2h(src[(size_t)j * HW_]);
        _Float16* dst = xt + ((size_t)b * HW_ + pix) * 64 + g * 16;
        *(hf8*)dst       = *(hf8*)&vals[0];
        *(hf8*)(dst + 8) = *(hf8*)&vals[8];
    } else {
        if (bid == 1024 && tid < 64) xt[(size_t)ZOFF + tid] = (_Float16)0.0f;
        const int idx = (bid - 1024) * 256 + tid;   // 0..36863
        {   // dwh: 9*64*64 = 36864
            const int k = idx / (COUT_ * CIN_);
            const int r = idx % (COUT_ * CIN_);
            const int o = r >> 6, c = r & 63;
            dwh[idx] = f2h(dw[(o * CIN_ + c) * KK_ + k]);
        }
        if (idx < KK_ * 32 * CIN_) {                // 18432
            const int k = idx / (32 * CIN_);
            const int r = idx % (32 * CIN_);
            const int co = r >> 6, c = r & 63;
            owh[idx] = f2h(co < OFFC_ ? ow[(co * CIN_ + c) * KK_ + k] : 0.0f);
        }
    }
}

// Two named corner-register sets (static indexing -> registers, no scratch).
// Staging mapping (R8/R12/R14-verified): 4 lanes/pixel, sub = 16B ch chunk.
// Addresses precomputed in adr[t][c] (invalid corners -> ZOFF zero row, so
// no masking anywhere); weights precomputed in pmv[t][c].
#define DECL_SET(S) \
    hf8 r00a##S, r00b##S, r01a##S, r01b##S, r10a##S, r10b##S, r11a##S, r11b##S;

#define LOAD_SET(S, t) { \
    r00a##S = *(const hf8*)(xt + adr[t][0]); r00b##S = *(const hf8*)(xt + adr[t][0] + 32); \
    r01a##S = *(const hf8*)(xt + adr[t][1]); r01b##S = *(const hf8*)(xt + adr[t][1] + 32); \
    r10a##S = *(const hf8*)(xt + adr[t][2]); r10b##S = *(const hf8*)(xt + adr[t][2] + 32); \
    r11a##S = *(const hf8*)(xt + adr[t][3]); r11b##S = *(const hf8*)(xt + adr[t][3] + 32); \
}

#define COMBINE_WRITE(S, t, dstbuf) { \
    const hf8 m00v = (hf8)f2h(pmv[t][0]); \
    const hf8 m01v = (hf8)f2h(pmv[t][1]); \
    const hf8 m10v = (hf8)f2h(pmv[t][2]); \
    const hf8 m11v = (hf8)f2h(pmv[t][3]); \
    const hf8 va = m00v * r00a##S + m01v * r01a##S + m10v * r10a##S + m11v * r11a##S; \
    const hf8 vb = m00v * r00b##S + m01v * r01b##S + m10v * r10b##S + m11v * r11b##S; \
    const int cA = sub; \
    const int cB = sub + 4; \
    *(hf8*)&u.smp[(dstbuf) * 4096 + p * 64 + ((cA ^ (p & 7)) << 3)] = va; \
    *(hf8*)&u.smp[(dstbuf) * 4096 + p * 64 + ((cB ^ (p & 7)) << 3)] = vb; \
}

// ---------------------------------------------------------------------------
// Fused kernel (R14 structure + precomputed addresses/weights). Block = 256
// thr (4 waves) = 64 pixels. grid 1024, XCD-swizzled. Phase A: offset conv
// via MFMA from LDS patch. Phase B: 4-buffer 2-tap rounds, 5 barriers;
// steady-state rounds issue gathers with zero leading address work.
// ---------------------------------------------------------------------------
__global__ __launch_bounds__(256, 3) void fused_deform_mfma(
    const _Float16* __restrict__ xt,  // (B,HW,64)+pad fp16 channels-last
    const _Float16* __restrict__ owh, // [9][32][64] fp16
    const float* __restrict__ obias,  // (18,)
    const _Float16* __restrict__ dwh, // [9][64][64] fp16
    const float* __restrict__ dbias,  // (64,)
    float* __restrict__ out)          // (B,64,128,128) f32
{
    __shared__ union {
        _Float16 xtl[3 * 66 * 64];   // phase A: [y][q][c], q=col+1  (25.3 KB)
        _Float16 smp[4 * 64 * 64];   // phase B: [buf0..3][p][c]     (32 KB)
    } u;
    __shared__ float offs[OFFC_ * TILE_];

    // ---- XCD-aware block swizzle (1024 % 8 == 0 -> simple bijection) ----
    const int lin  = blockIdx.x;
    const int nid  = (lin & 7) * 128 + (lin >> 3);
    const int b    = nid >> 8;
    const int tile = nid & 255;

    const int tid = threadIdx.x;
    const int pixbase = tile * TILE_;
    const int ho    = pixbase >> 7;
    const int wbase = pixbase & (W_ - 1);
    const int lane  = tid & 63;
    const int wv    = tid >> 6;              // wave 0..3
    const int arow  = lane & 15;             // MFMA frag row/col index
    const int kseg  = lane >> 4;             // 0..3

    const _Float16* xbt = xt + (size_t)b * HW_ * 64;

    // ---- stage x patch (3 rows x 66 cols x 64 ch) once, swizzled ----
    for (int base = 0; base < 3 * 66 * 8; base += 256) {
        const int idx = base + tid;
        if (idx < 3 * 66 * 8) {
            const int cc = idx & 7;          // c-chunk
            const int qy = idx >> 3;         // 0..197
            const int y  = qy / 66;
            const int q  = qy - y * 66;
            const int gy = ho + y - 1;
            const int gx = wbase + q - 1;
            hf8 v;
            if (gy >= 0 && gy < H_ && gx >= 0 && gx < W_) {
                v = *(const hf8*)&xbt[(size_t)(gy * W_ + gx) * 64 + cc * 8];
            } else {
                v = (hf8)(_Float16)0.0f;
            }
            *(hf8*)&u.xtl[(y * 66 + q) * 64 + ((cc ^ (q & 7)) << 3)] = v;
        }
    }
    __syncthreads();

    // ---- Phase A: offset conv via MFMA (R14-verified) ----
    {
        const int m = wv & 1;                // co tile
        const int h = wv >> 1;               // pixel half
        f32x4 acca[2];
        acca[0] = (f32x4)0.f; acca[1] = (f32x4)0.f;
        for (int t = 0; t < KK_; ++t) {
            const int ky = t / 3, kx = t % 3;
            #pragma unroll
            for (int kc = 0; kc < 2; ++kc) {
                const int cbase = kc * 32 + kseg * 8;
                const hf8 afrag = *(const hf8*)&owh[(t * 32 + m * 16 + arow) * 64 + cbase];
                const int cchunk = cbase >> 3;
                #pragma unroll
                for (int nt = 0; nt < 2; ++nt) {
                    const int pp = h * 32 + nt * 16 + arow;
                    const int q = pp + kx;
                    const hf8 bfrag = *(const hf8*)&u.xtl[(ky * 66 + q) * 64 + ((cchunk ^ (q & 7)) << 3)];
                    acca[nt] = __builtin_amdgcn_mfma_f32_16x16x32_f16(afrag, bfrag, acca[nt], 0, 0, 0);
                }
            }
        }
        #pragma unroll
        for (int nt = 0; nt < 2; ++nt) {
            #pragma unroll
            for (int r = 0; r < 4; ++r) {
                const int co = m * 16 + kseg * 4 + r;
                if (co < OFFC_) {
                    const int pp = h * 32 + nt * 16 + arow;
                    offs[co * TILE_ + pp] = acca[nt][r] + obias[co];
                }
            }
        }
    }
    __syncthreads();   // offs ready; xtl dead -> smp may reuse the union

    // ---- Phase B precompute: all 9 taps' addresses + bilinear weights ----
    const int pix16 = lane >> 2;             // 0..15 pixel within wave
    const int sub   = lane & 3;              // channel sub-chunk
    const int p     = wv * 16 + pix16;       // pixel 0..63
    const int wo    = wbase + p;
    const int boff  = b * HW_ * 64 + sub * 8;

    int   adr[KK_][4];
    float pmv[KK_][4];
    #pragma unroll
    for (int t = 0; t < KK_; ++t) {
        const int ky = t / 3, kx = t % 3;
        const float dy = offs[(2 * t + 0) * TILE_ + p];
        const float dx = offs[(2 * t + 1) * TILE_ + p];
        const float ys = (float)(ho + ky - 1) + dy;
        const float xs = (float)(wo + kx - 1) + dx;
        const float y0f = floorf(ys), x0f = floorf(xs);
        const float ly = ys - y0f, lx = xs - x0f;
        const int y0 = (int)y0f, x0 = (int)x0f;
        const int y1 = y0 + 1,   x1 = x0 + 1;
        const bool y0v = (y0 >= 0) & (y0 < H_);
        const bool y1v = (y1 >= 0) & (y1 < H_);
        const bool x0v = (x0 >= 0) & (x0 < W_);
        const bool x1v = (x1 >= 0) & (x1 < W_);
        pmv[t][0] = (1.f - ly) * (1.f - lx);
        pmv[t][1] = (1.f - ly) * lx;
        pmv[t][2] = ly * (1.f - lx);
        pmv[t][3] = ly * lx;
        const int y0c = min(max(y0, 0), H_ - 1);
        const int y1c = min(max(y1, 0), H_ - 1);
        const int x0c = min(max(x0, 0), W_ - 1);
        const int x1c = min(max(x1, 0), W_ - 1);
        const int zo = ZOFF + sub * 8;
        adr[t][0] = (y0v & x0v) ? boff + (y0c * W_ + x0c) * 64 : zo;
        adr[t][1] = (y0v & x1v) ? boff + (y0c * W_ + x1c) * 64 : zo;
        adr[t][2] = (y1v & x0v) ? boff + (y1c * W_ + x0c) * 64 : zo;
        adr[t][3] = (y1v & x1v) ? boff + (y1c * W_ + x1c) * 64 : zo;
    }

    DECL_SET(A)
    DECL_SET(B)

    f32x4 accb[4];
    #pragma unroll
    for (int nt = 0; nt < 4; ++nt) accb[nt] = (f32x4)0.f;

    auto mfmaTap = [&](int t, int srcbuf) {
        #pragma unroll
        for (int kc = 0; kc < 2; ++kc) {
            const int cbase = kc * 32 + kseg * 8;
            const hf8 afrag = *(const hf8*)&dwh[(t * 64 + wv * 16 + arow) * 64 + cbase];
            const int cchunk = cbase >> 3;
            #pragma unroll
            for (int nt = 0; nt < 4; ++nt) {
                const int pp = nt * 16 + arow;
                const hf8 bfrag = *(const hf8*)&u.smp[srcbuf * 4096 + pp * 64 + ((cchunk ^ (pp & 7)) << 3)];
                accb[nt] = __builtin_amdgcn_mfma_f32_16x16x32_f16(afrag, bfrag, accb[nt], 0, 0, 0);
            }
        }
    };

    // prologue: taps 0,1 -> buffers 0,1
    LOAD_SET(A, 0)
    LOAD_SET(B, 1)
    COMBINE_WRITE(A, 0, 0)
    COMBINE_WRITE(B, 1, 1)
    __syncthreads();

    // rounds r=0..3: stage taps {2r+2,2r+3} -> pair[(r+1)&1],
    //                compute {2r,2r+1} <- pair[r&1]
    #pragma unroll
    for (int r = 0; r < 4; ++r) {
        const int ta = 2 * r + 2;
        const int tb = 2 * r + 3;
        const int sb = ((r + 1) & 1) * 2;    // stage pair base
        const int cb = (r & 1) * 2;          // compute pair base
        LOAD_SET(A, ta)                      // ta = 2,4,6,8 all < 9
        if (tb < KK_) LOAD_SET(B, tb)
        mfmaTap(2 * r,     cb + 0);
        mfmaTap(2 * r + 1, cb + 1);
        COMBINE_WRITE(A, ta, sb + 0)
        if (tb < KK_) COMBINE_WRITE(B, tb, sb + 1)
        __syncthreads();
    }
    // final tap 8 (staged in round 3 -> buffer 0)
    mfmaTap(8, 0);

    // ---- epilogue: o = wv*16 + kseg*4 + r, pixel = pixbase + pp ----
    float* ob = out + (size_t)b * COUT_ * HW_ + pixbase;
    #pragma unroll
    for (int nt = 0; nt < 4; ++nt) {
        const int pp = nt * 16 + arow;
        #pragma unroll
        for (int r = 0; r < 4; ++r) {
            const int o = wv * 16 + kseg * 4 + r;
            ob[(size_t)o * HW_ + pp] = accb[nt][r] + dbias[o];
        }
    }
}

extern "C" void kernel_launch(void* const* d_in, const int* in_sizes, int n_in,
                              void* d_out, int out_size, void* d_ws, size_t ws_size,
                              hipStream_t stream) {
    const float* x        = (const float*)d_in[0];
    const float* offset_w = (const float*)d_in[1];
    const float* offset_b = (const float*)d_in[2];
    const float* deform_w = (const float*)d_in[3];
    const float* deform_b = (const float*)d_in[4];
    float* out = (float*)d_out;

    _Float16* dwh = (_Float16*)d_ws;                       // 73728 B
    _Float16* owh = (_Float16*)((char*)d_ws + 73728);      // 36864 B
    _Float16* xt  = (_Float16*)((char*)d_ws + 110592);     // 8 MB + 128 B pad

    prep_all<<<1024 + 144, 256, 0, stream>>>(x, offset_w, deform_w, xt, dwh, owh);

    fused_deform_mfma<<<1024, 256, 0, stream>>>(xt, owh, offset_b, dwh, deform_b, out);
}

// Round 18
// 44.075 us; speedup vs baseline: 1.0783x; 1.0783x over previous
//
#include <hip/hip_runtime.h>
#include <hip/hip_bf16.h>

#define B_    4
#define CIN_  64
#define H_    128
#define W_    128
#define COUT_ 64
#define KK_   9
#define OFFC_ 18
#define HW_   (H_*W_)
#define TILE_ 64

typedef _Float16 hf8 __attribute__((ext_vector_type(8)));   // 8 fp16 (4 VGPRs)
typedef float f32x4  __attribute__((ext_vector_type(4)));

__device__ inline _Float16 f2h(float f) { return (_Float16)f; }

// ---------------------------------------------------------------------------
// Prep (single launch): blocks 0..1023 transpose x -> NHWC fp16 via an
// LDS-tiled transpose (coalesced reads AND 128B-segment writes);
// blocks 1024..1167 repack weights to fp16 MFMA layout.
//   xt[b][y][x][c]   dwh[k][o][c] (9*64*64)   owh[k][co<32][c] (pad rows 0)
// ---------------------------------------------------------------------------
__global__ __launch_bounds__(256) void prep_all(
    const float* __restrict__ x,
    const float* __restrict__ ow, const float* __restrict__ dw,
    _Float16* __restrict__ xt, _Float16* __restrict__ dwh, _Float16* __restrict__ owh)
{
    __shared__ _Float16 t[64 * 66];          // 64 px x 64 ch, stride 66 (8.25 KB)
    const int tid = threadIdx.x;
    const int bid = blockIdx.x;
    if (bid < 1024) {
        const int b    = bid >> 8;
        const int pb   = bid & 255;
        const int pix0 = pb * 64;
        const int p    = tid & 63;           // pixel
        const int g    = tid >> 6;           // channel group (16 ch)
        // coalesced reads: per instr, 64 lanes read 256B of one channel row
        const float* src = x + ((size_t)b * CIN_ + g * 16) * HW_ + pix0 + p;
        #pragma unroll
        for (int j = 0; j < 16; ++j)
            t[p * 66 + g * 16 + j] = f2h(src[(size_t)j * HW_]);
        __syncthreads();
        // writes: 8 lanes cover one pixel's 128B channel row -> 8 segments/instr
        #pragma unroll
        for (int k = 0; k < 2; ++k) {
            const int p2  = k * 32 + (tid >> 3);
            const int sub = tid & 7;
            _Float16 vals[8];
            #pragma unroll
            for (int j = 0; j < 8; ++j) vals[j] = t[p2 * 66 + sub * 8 + j];
            *(hf8*)&xt[((size_t)b * HW_ + pix0 + p2) * 64 + sub * 8] = *(hf8*)vals;
        }
    } else {
        const int idx = (bid - 1024) * 256 + tid;   // 0..36863
        {   // dwh: 9*64*64 = 36864
            const int k = idx / (COUT_ * CIN_);
            const int r = idx % (COUT_ * CIN_);
            const int o = r >> 6, c = r & 63;
            dwh[idx] = f2h(dw[(o * CIN_ + c) * KK_ + k]);
        }
        if (idx < KK_ * 32 * CIN_) {                // 18432
            const int k = idx / (32 * CIN_);
            const int r = idx % (32 * CIN_);
            const int co = r >> 6, c = r & 63;
            owh[idx] = f2h(co < OFFC_ ? ow[(co * CIN_ + c) * KK_ + k] : 0.0f);
        }
    }
}

// Two named corner-register sets (static indexing -> registers, no scratch).
// Staging mapping (R8/R12-verified): 4 lanes per pixel, sub = 16B ch chunk.
#define DECL_SET(S) \
    hf8 r00a##S, r00b##S, r01a##S, r01b##S, r10a##S, r10b##S, r11a##S, r11b##S; \
    float pm0##S, pm1##S, pm2##S, pm3##S;

#define LOAD_SET(S, t) { \
    const int ky = (t) / 3, kx = (t) % 3; \
    const float dy = offs[(2 * (t) + 0) * TILE_ + p]; \
    const float dx = offs[(2 * (t) + 1) * TILE_ + p]; \
    const float ys = (float)(ho + ky - 1) + dy; \
    const float xs = (float)(wo + kx - 1) + dx; \
    const float y0f = floorf(ys), x0f = floorf(xs); \
    const float ly = ys - y0f, lx = xs - x0f; \
    const int y0 = (int)y0f, x0 = (int)x0f; \
    const int y1 = y0 + 1,   x1 = x0 + 1; \
    const bool y0v = (y0 >= 0) & (y0 < H_); \
    const bool y1v = (y1 >= 0) & (y1 < H_); \
    const bool x0v = (x0 >= 0) & (x0 < W_); \
    const bool x1v = (x1 >= 0) & (x1 < W_); \
    pm0##S = (y0v & x0v) ? (1.f - ly) * (1.f - lx) : 0.f; \
    pm1##S = (y0v & x1v) ? (1.f - ly) * lx         : 0.f; \
    pm2##S = (y1v & x0v) ? ly * (1.f - lx)         : 0.f; \
    pm3##S = (y1v & x1v) ? ly * lx                 : 0.f; \
    const int y0c = min(max(y0, 0), H_ - 1); \
    const int y1c = min(max(y1, 0), H_ - 1); \
    const int x0c = min(max(x0, 0), W_ - 1); \
    const int x1c = min(max(x1, 0), W_ - 1); \
    const _Float16* c00 = xbt + (size_t)(y0c * W_ + x0c) * 64 + sub * 8; \
    const _Float16* c01 = xbt + (size_t)(y0c * W_ + x1c) * 64 + sub * 8; \
    const _Float16* c10 = xbt + (size_t)(y1c * W_ + x0c) * 64 + sub * 8; \
    const _Float16* c11 = xbt + (size_t)(y1c * W_ + x1c) * 64 + sub * 8; \
    r00a##S = *(const hf8*)(c00); r00b##S = *(const hf8*)(c00 + 32); \
    r01a##S = *(const hf8*)(c01); r01b##S = *(const hf8*)(c01 + 32); \
    r10a##S = *(const hf8*)(c10); r10b##S = *(const hf8*)(c10 + 32); \
    r11a##S = *(const hf8*)(c11); r11b##S = *(const hf8*)(c11 + 32); \
}

// packed-fp16 combine: no cvt chain, values feed MFMA B-frags directly
#define COMBINE_WRITE(S, dstbuf) { \
    const hf8 m00v = (hf8)f2h(pm0##S); \
    const hf8 m01v = (hf8)f2h(pm1##S); \
    const hf8 m10v = (hf8)f2h(pm2##S); \
    const hf8 m11v = (hf8)f2h(pm3##S); \
    const hf8 va = m00v * r00a##S + m01v * r01a##S + m10v * r10a##S + m11v * r11a##S; \
    const hf8 vb = m00v * r00b##S + m01v * r01b##S + m10v * r10b##S + m11v * r11b##S; \
    const int cA = sub; \
    const int cB = sub + 4; \
    *(hf8*)&u.smp[(dstbuf) * 4096 + p * 64 + ((cA ^ (p & 7)) << 3)] = va; \
    *(hf8*)&u.smp[(dstbuf) * 4096 + p * 64 + ((cB ^ (p & 7)) << 3)] = vb; \
}

// ---------------------------------------------------------------------------
// Fused kernel (R14-verified, unchanged). Block = 256 thr (4 waves) =
// 64 pixels. grid 1024, XCD-swizzled. Phase A: offset conv via MFMA from LDS
// patch. Phase B: 4-buffer 2-tap rounds, 5 barriers.
// ---------------------------------------------------------------------------
__global__ __launch_bounds__(256, 4) void fused_deform_mfma(
    const _Float16* __restrict__ xt,  // (B,HW,64) fp16 channels-last
    const _Float16* __restrict__ owh, // [9][32][64] fp16
    const float* __restrict__ obias,  // (18,)
    const _Float16* __restrict__ dwh, // [9][64][64] fp16
    const float* __restrict__ dbias,  // (64,)
    float* __restrict__ out)          // (B,64,128,128) f32
{
    __shared__ union {
        _Float16 xtl[3 * 66 * 64];   // phase A: [y][q][c], q=col+1  (25.3 KB)
        _Float16 smp[4 * 64 * 64];   // phase B: [buf0..3][p][c]     (32 KB)
    } u;
    __shared__ float offs[OFFC_ * TILE_];

    // ---- XCD-aware block swizzle (1024 % 8 == 0 -> simple bijection) ----
    const int lin  = blockIdx.x;
    const int nid  = (lin & 7) * 128 + (lin >> 3);
    const int b    = nid >> 8;
    const int tile = nid & 255;

    const int tid = threadIdx.x;
    const int pixbase = tile * TILE_;
    const int ho    = pixbase >> 7;
    const int wbase = pixbase & (W_ - 1);
    const int lane  = tid & 63;
    const int wv    = tid >> 6;              // wave 0..3
    const int arow  = lane & 15;             // MFMA frag row/col index
    const int kseg  = lane >> 4;             // 0..3

    const _Float16* xbt = xt + (size_t)b * HW_ * 64;

    // ---- stage x patch (3 rows x 66 cols x 64 ch) once, swizzled ----
    for (int base = 0; base < 3 * 66 * 8; base += 256) {
        const int idx = base + tid;
        if (idx < 3 * 66 * 8) {
            const int cc = idx & 7;          // c-chunk
            const int qy = idx >> 3;         // 0..197
            const int y  = qy / 66;
            const int q  = qy - y * 66;
            const int gy = ho + y - 1;
            const int gx = wbase + q - 1;
            hf8 v;
            if (gy >= 0 && gy < H_ && gx >= 0 && gx < W_) {
                v = *(const hf8*)&xbt[(size_t)(gy * W_ + gx) * 64 + cc * 8];
            } else {
                v = (hf8)(_Float16)0.0f;
            }
            *(hf8*)&u.xtl[(y * 66 + q) * 64 + ((cc ^ (q & 7)) << 3)] = v;
        }
    }
    __syncthreads();

    // ---- Phase A: offset conv via MFMA ----
    {
        const int m = wv & 1;                // co tile
        const int h = wv >> 1;               // pixel half
        f32x4 acca[2];
        acca[0] = (f32x4)0.f; acca[1] = (f32x4)0.f;
        for (int t = 0; t < KK_; ++t) {
            const int ky = t / 3, kx = t % 3;
            #pragma unroll
            for (int kc = 0; kc < 2; ++kc) {
                const int cbase = kc * 32 + kseg * 8;
                const hf8 afrag = *(const hf8*)&owh[(t * 32 + m * 16 + arow) * 64 + cbase];
                const int cchunk = cbase >> 3;
                #pragma unroll
                for (int nt = 0; nt < 2; ++nt) {
                    const int pp = h * 32 + nt * 16 + arow;
                    const int q = pp + kx;
                    const hf8 bfrag = *(const hf8*)&u.xtl[(ky * 66 + q) * 64 + ((cchunk ^ (q & 7)) << 3)];
                    acca[nt] = __builtin_amdgcn_mfma_f32_16x16x32_f16(afrag, bfrag, acca[nt], 0, 0, 0);
                }
            }
        }
        #pragma unroll
        for (int nt = 0; nt < 2; ++nt) {
            #pragma unroll
            for (int r = 0; r < 4; ++r) {
                const int co = m * 16 + kseg * 4 + r;
                if (co < OFFC_) {
                    const int pp = h * 32 + nt * 16 + arow;
                    offs[co * TILE_ + pp] = acca[nt][r] + obias[co];
                }
            }
        }
    }
    __syncthreads();   // offs ready; xtl dead -> smp may reuse the union

    // ---- Phase B: 4-buffer 2-tap rounds (R12-verified schedule) ----
    const int pix16 = lane >> 2;             // 0..15 pixel within wave
    const int sub   = lane & 3;              // channel sub-chunk
    const int p     = wv * 16 + pix16;       // pixel 0..63
    const int wo    = wbase + p;

    DECL_SET(A)
    DECL_SET(B)

    f32x4 accb[4];
    #pragma unroll
    for (int nt = 0; nt < 4; ++nt) accb[nt] = (f32x4)0.f;

    auto mfmaTap = [&](int t, int srcbuf) {
        #pragma unroll
        for (int kc = 0; kc < 2; ++kc) {
            const int cbase = kc * 32 + kseg * 8;
            const hf8 afrag = *(const hf8*)&dwh[(t * 64 + wv * 16 + arow) * 64 + cbase];
            const int cchunk = cbase >> 3;
            #pragma unroll
            for (int nt = 0; nt < 4; ++nt) {
                const int pp = nt * 16 + arow;
                const hf8 bfrag = *(const hf8*)&u.smp[srcbuf * 4096 + pp * 64 + ((cchunk ^ (pp & 7)) << 3)];
                accb[nt] = __builtin_amdgcn_mfma_f32_16x16x32_f16(afrag, bfrag, accb[nt], 0, 0, 0);
            }
        }
    };

    // prologue: taps 0,1 -> buffers 0,1
    LOAD_SET(A, 0)
    LOAD_SET(B, 1)
    COMBINE_WRITE(A, 0)
    COMBINE_WRITE(B, 1)
    __syncthreads();

    // rounds r=0..3: stage taps {2r+2,2r+3} -> pair[(r+1)&1],
    //                compute {2r,2r+1} <- pair[r&1]
    #pragma unroll
    for (int r = 0; r < 4; ++r) {
        const int ta = 2 * r + 2;
        const int tb = 2 * r + 3;
        const int sb = ((r + 1) & 1) * 2;    // stage pair base
        const int cb = (r & 1) * 2;          // compute pair base
        LOAD_SET(A, ta)                      // ta = 2,4,6,8 all < 9
        if (tb < KK_) LOAD_SET(B, tb)
        mfmaTap(2 * r,     cb + 0);
        mfmaTap(2 * r + 1, cb + 1);
        COMBINE_WRITE(A, sb + 0)
        if (tb < KK_) COMBINE_WRITE(B, sb + 1)
        __syncthreads();
    }
    // final tap 8 (staged in round 3 -> buffer 0)
    mfmaTap(8, 0);

    // ---- epilogue: o = wv*16 + kseg*4 + r, pixel = pixbase + pp ----
    float* ob = out + (size_t)b * COUT_ * HW_ + pixbase;
    #pragma unroll
    for (int nt = 0; nt < 4; ++nt) {
        const int pp = nt * 16 + arow;
        #pragma unroll
        for (int r = 0; r < 4; ++r) {
            const int o = wv * 16 + kseg * 4 + r;
            ob[(size_t)o * HW_ + pp] = accb[nt][r] + dbias[o];
        }
    }
}

extern "C" void kernel_launch(void* const* d_in, const int* in_sizes, int n_in,
                              void* d_out, int out_size, void* d_ws, size_t ws_size,
                              hipStream_t stream) {
    const float* x        = (const float*)d_in[0];
    const float* offset_w = (const float*)d_in[1];
    const float* offset_b = (const float*)d_in[2];
    const float* deform_w = (const float*)d_in[3];
    const float* deform_b = (const float*)d_in[4];
    float* out = (float*)d_out;

    _Float16* dwh = (_Float16*)d_ws;                       // 73728 B
    _Float16* owh = (_Float16*)((char*)d_ws + 73728);      // 36864 B
    _Float16* xt  = (_Float16*)((char*)d_ws + 110592);     // 8 MB NHWC fp16

    prep_all<<<1024 + 144, 256, 0, stream>>>(x, offset_w, deform_w, xt, dwh, owh);

    fused_deform_mfma<<<1024, 256, 0, stream>>>(xt, owh, offset_b, dwh, deform_b, out);
}